// Round 1
// baseline (28275.201 us; speedup 1.0000x reference)
//
#include <hip/hip_runtime.h>
#include <hip/hip_fp16.h>
#include <stdint.h>

// Problem constants (B,S,H,Q fixed by the reference)
#define BB 128
#define SS 256
#define HH 512
#define QQ 360

// ---------------- Threefry-2x32 (exact JAX semantics) ----------------
struct TF2 { uint32_t a, b; };

__host__ __device__ constexpr uint32_t rotl32(uint32_t x, int d) {
  return (x << d) | (x >> (32 - d));
}

__host__ __device__ constexpr TF2 threefry(uint32_t k0, uint32_t k1,
                                           uint32_t x0, uint32_t x1) {
  uint32_t ks[3] = {k0, k1, k0 ^ k1 ^ 0x1BD11BDAu};
  x0 += ks[0]; x1 += ks[1];
  const int R0[4] = {13, 15, 26, 6};
  const int R1[4] = {17, 29, 16, 24};
  for (int g = 0; g < 5; ++g) {
    const int* r = (g & 1) ? R1 : R0;
    for (int i = 0; i < 4; ++i) { x0 += x1; x1 = rotl32(x1, r[i]); x1 ^= x0; }
    x0 += ks[(g + 1) % 3];
    x1 += ks[(g + 2) % 3] + (uint32_t)(g + 1);
  }
  return TF2{x0, x1};
}

// Per-step sampling keys: key0 = jax.random.key(1) = (0,1);
// partitionable split: carry = TF(key,(0,0)), step key = TF(key,(0,1)).
struct KeyTab { uint32_t sk[256][2]; };
constexpr KeyTab make_keys() {
  KeyTab K{};
  uint32_t k0 = 0u, k1 = 1u;
  for (int t = 0; t < 256; ++t) {
    TF2 nk = threefry(k0, k1, 0u, 0u);
    TF2 sk = threefry(k0, k1, 0u, 1u);
    K.sk[t][0] = sk.a; K.sk[t][1] = sk.b;
    k0 = nk.a; k1 = nk.b;
  }
  return K;
}
__constant__ KeyTab c_keys = make_keys();

// ---------------- Phase A1: encT[b][h][s] = (inputs @ Wc + bc)^T ----------------
// grid (8 h-tiles, 128 b), 256 threads; 64h x 256s per block, K=512 via LDS.
__global__ __launch_bounds__(256) void k_enc(const float* __restrict__ inputs,
                                             const float* __restrict__ Wc,
                                             const float* __restrict__ bc,
                                             float* __restrict__ encT) {
  const int ht = blockIdx.x;
  const int b  = blockIdx.y;
  const int tid = threadIdx.x;
  const int ts = tid & 63, th = tid >> 6;
  __shared__ float Xs[32 * 260];   // [k][s] transposed inputs tile
  __shared__ float Ws[32 * 64];    // [k][h] Wc tile
  float acc[16][4];
#pragma unroll
  for (int i = 0; i < 16; ++i)
#pragma unroll
    for (int j = 0; j < 4; ++j) acc[i][j] = 0.f;

  const float* Arow = inputs + ((size_t)b * SS + tid) * HH;
  for (int kk = 0; kk < HH; kk += 32) {
    const float4* ip = (const float4*)(Arow + kk);
#pragma unroll
    for (int e = 0; e < 8; ++e) {
      float4 w = ip[e];
      Xs[(e * 4 + 0) * 260 + tid] = w.x;
      Xs[(e * 4 + 1) * 260 + tid] = w.y;
      Xs[(e * 4 + 2) * 260 + tid] = w.z;
      Xs[(e * 4 + 3) * 260 + tid] = w.w;
    }
    {
      int kw = tid >> 3, hw = (tid & 7) * 8;
      const float4* wp = (const float4*)(Wc + (size_t)(kk + kw) * HH + ht * 64 + hw);
      float4 w0 = wp[0], w1 = wp[1];
      float* d = Ws + kw * 64 + hw;
      ((float4*)d)[0] = w0; ((float4*)d)[1] = w1;
    }
    __syncthreads();
#pragma unroll 8
    for (int k = 0; k < 32; ++k) {
      float xr[4];
#pragma unroll
      for (int j = 0; j < 4; ++j) xr[j] = Xs[k * 260 + ts + 64 * j];
      const float4* wr4 = (const float4*)(Ws + k * 64 + th * 16);
#pragma unroll
      for (int i4 = 0; i4 < 4; ++i4) {
        float4 w = wr4[i4];
        float wv[4] = {w.x, w.y, w.z, w.w};
#pragma unroll
        for (int c = 0; c < 4; ++c)
#pragma unroll
          for (int j = 0; j < 4; ++j) acc[i4 * 4 + c][j] += wv[c] * xr[j];
      }
    }
    __syncthreads();
  }
#pragma unroll
  for (int i = 0; i < 16; ++i) {
    int h = ht * 64 + th * 16 + i;
    float bcv = bc[h];
    float* orow = encT + (size_t)b * (HH * SS) + (size_t)h * SS + ts;
#pragma unroll
    for (int j = 0; j < 4; ++j) orow[64 * j] = acc[i][j] + bcv;
  }
}

// ---------------- Phase A2: G[k][b][j][q] = inputs[b,j,:] @ Wq[k] ----------------
// grid (6 q-tiles, 128 b, 3 k), 256 threads; 64q x 256j per block.
template <typename GT>
__global__ __launch_bounds__(256) void k_G(const float* __restrict__ inputs,
                                           const float* __restrict__ Wq,
                                           GT* __restrict__ G) {
  const int qt = blockIdx.x;
  const int b  = blockIdx.y;
  const int k  = blockIdx.z;
  const int tid = threadIdx.x;
  const int ql = tid & 63, tj = tid >> 6;
  __shared__ float Xs[32 * 260];
  __shared__ float Ws[32 * 64];
  float acc[64];
#pragma unroll
  for (int j = 0; j < 64; ++j) acc[j] = 0.f;
  const int q = qt * 64 + ql;
  const float* Arow = inputs + ((size_t)b * SS + tid) * HH;
  const float* Wqk = Wq + (size_t)k * HH * QQ;
  for (int kk = 0; kk < HH; kk += 32) {
    const float4* ip = (const float4*)(Arow + kk);
#pragma unroll
    for (int e = 0; e < 8; ++e) {
      float4 w = ip[e];
      Xs[(e * 4 + 0) * 260 + tid] = w.x;
      Xs[(e * 4 + 1) * 260 + tid] = w.y;
      Xs[(e * 4 + 2) * 260 + tid] = w.z;
      Xs[(e * 4 + 3) * 260 + tid] = w.w;
    }
    {
      int hh = tid >> 3, qw = (tid & 7) * 8;
      const float* src = Wqk + (size_t)(kk + hh) * QQ;
      float* d = Ws + hh * 64 + qw;
#pragma unroll
      for (int e = 0; e < 8; ++e) {
        int qg = qt * 64 + qw + e;
        d[e] = (qg < QQ) ? src[qg] : 0.f;
      }
    }
    __syncthreads();
#pragma unroll 4
    for (int k2 = 0; k2 < 32; ++k2) {
      float wr = Ws[k2 * 64 + ql];
      const float4* xp = (const float4*)(Xs + k2 * 260 + tj * 64);
#pragma unroll
      for (int j4 = 0; j4 < 16; ++j4) {
        float4 x = xp[j4];
        acc[j4 * 4 + 0] += wr * x.x;
        acc[j4 * 4 + 1] += wr * x.y;
        acc[j4 * 4 + 2] += wr * x.z;
        acc[j4 * 4 + 3] += wr * x.w;
      }
    }
    __syncthreads();
  }
  if (q < QQ) {
    GT* gb = G + (((size_t)k * BB + b) * SS + tj * 64) * QQ + q;
#pragma unroll
    for (int j = 0; j < 64; ++j) gb[(size_t)j * QQ] = (GT)acc[j];
  }
}

// ---------------- Main scan: block = batch, 256 steps internal ----------------
template <typename GT>
__global__ __launch_bounds__(512, 2) void k_scan(
    const float* __restrict__ w_q, const float* __restrict__ v,
    const float* __restrict__ encT, const GT* __restrict__ G,
    float* __restrict__ out, double* __restrict__ lpb, double* __restrict__ entb) {
  const int b = blockIdx.x;
  const int tid = threadIdx.x;
  const int lane = tid & 63;
  const int wid = tid >> 6;

  __shared__ float q_s[QQ];
  __shared__ float eq_s[HH];
  __shared__ float v_s[HH];
  __shared__ double red_d[512];
  __shared__ double m_s[SS];
  __shared__ float mask_s[SS];
  __shared__ int hist[3];
  __shared__ double wz[4]; __shared__ int wi[4];
  __shared__ double wm[4];
  __shared__ double ws1[4], ws2[4];
  __shared__ int idxB; __shared__ double MB;

  v_s[tid] = v[tid & (HH - 1)];   // tid<512 == HH
  if (tid < SS) mask_s[tid] = 0.f;
  if (tid < 3) hist[tid] = -1;
  __syncthreads();

  double lp_acc = 0.0, ent_acc = 0.0;
  int first_idx = 0;
  const float* encB = encT + (size_t)b * (HH * SS);

  for (int t = 0; t < SS; ++t) {
    // ---- P1: query[q] = relu(sum_k G[k][b][hist[k]][q])
    if (tid < QQ) {
      float s3 = 0.f;
#pragma unroll
      for (int k = 0; k < 3; ++k) {
        int j = hist[k];
        if (j >= 0) s3 += (float)G[(((size_t)k * BB + b) * SS + j) * QQ + tid];
      }
      q_s[tid] = fmaxf(s3, 0.f);
    }
    __syncthreads();
    // ---- P2: eq[h] = sum_q query[q] * w_q[q][h]
    {
      double a0 = 0.0, a1 = 0.0;
      const float* wcol = w_q + tid;
#pragma unroll 4
      for (int qq2 = 0; qq2 < QQ; qq2 += 2) {
        a0 += (double)q_s[qq2]     * (double)wcol[(size_t)qq2 * HH];
        a1 += (double)q_s[qq2 + 1] * (double)wcol[(size_t)(qq2 + 1) * HH];
      }
      eq_s[tid] = (float)(a0 + a1);
    }
    __syncthreads();
    // ---- P3: scores[s] = sum_h v[h]*tanh(enc[b,s,h]+eq[h]) (h split in two halves)
    {
      int s = tid & 255, hh2 = tid >> 8;
      const float* ep = encB + (size_t)(hh2 * 256) * SS + s;
      const float* eqp = eq_s + hh2 * 256;
      const float* vp = v_s + hh2 * 256;
      double part = 0.0;
#pragma unroll 4
      for (int h = 0; h < 256; ++h) {
        float a = ep[(size_t)h * SS] + eqp[h];
        part += (double)vp[h] * (double)tanhf(a);
      }
      red_d[tid] = part;
    }
    __syncthreads();
    // ---- P4: logits, gumbel, argmax / max reductions
    if (tid < SS) {
      int s = tid;
      double scd = red_d[s] + red_d[s + 256];
      double logit = 10.0 * tanh(scd);
      double masked = (mask_s[s] != 0.f) ? fmax(logit - 1.0e8, -1.0e8) : logit;
      m_s[s] = masked;
      uint32_t jj = (uint32_t)(b * SS + s);
      TF2 o = threefry(c_keys.sk[t][0], c_keys.sk[t][1], 0u, jj);
      uint32_t bits = o.b;
      float fb = __uint_as_float((bits >> 9) | 0x3f800000u) - 1.0f;
      if (fb == 0.0f) fb = 1.17549435e-38f;
      double g = -log(-log((double)fb));
      double z = masked + g;
      int si = s;
#pragma unroll
      for (int off = 32; off; off >>= 1) {
        double zo = __shfl_xor(z, off);
        int io = __shfl_xor(si, off);
        if (zo > z || (zo == z && io < si)) { z = zo; si = io; }
      }
      double mx = masked;
#pragma unroll
      for (int off = 32; off; off >>= 1) mx = fmax(mx, __shfl_xor(mx, off));
      if (lane == 0) { wz[wid] = z; wi[wid] = si; wm[wid] = mx; }
    }
    __syncthreads();
    if (tid == 0) {
      double zb = wz[0]; int ib = wi[0];
#pragma unroll
      for (int w = 1; w < 4; ++w)
        if (wz[w] > zb || (wz[w] == zb && wi[w] < ib)) { zb = wz[w]; ib = wi[w]; }
      idxB = ib;
      MB = fmax(fmax(wm[0], wm[1]), fmax(wm[2], wm[3]));
    }
    __syncthreads();
    int idx = idxB;
    if (tid < SS) {
      double masked = m_s[tid];
      double e = exp(masked - MB);
      double em = e * masked;
#pragma unroll
      for (int off = 32; off; off >>= 1) { e += __shfl_xor(e, off); em += __shfl_xor(em, off); }
      if (lane == 0) { ws1[wid] = e; ws2[wid] = em; }
    }
    __syncthreads();
    if (tid == 0) {
      double S1 = ws1[0] + ws1[1] + ws1[2] + ws1[3];
      double S2 = ws2[0] + ws2[1] + ws2[2] + ws2[3];
      double lse = MB + log(S1);
      lp_acc += m_s[idx] - lse;
      ent_acc += lse - S2 / S1;
      out[b * 257 + t] = (float)idx;
      mask_s[idx] = 1.0f;
      hist[0] = hist[1]; hist[1] = hist[2]; hist[2] = idx;
    }
    if (t == 0) first_idx = idx;
    __syncthreads();
  }
  if (tid == 0) {
    out[b * 257 + 256] = (float)first_idx;   // close the loop
    lpb[b] = lp_acc;
    entb[b] = ent_acc;
  }
}

// ---------------- Final deterministic reduction ----------------
__global__ void k_final(const double* __restrict__ lpb,
                        const double* __restrict__ entb, float* __restrict__ out) {
  if (threadIdx.x == 0) {
    double a = 0.0, c = 0.0;
    for (int i = 0; i < BB; ++i) { a += lpb[i]; c += entb[i]; }
    out[BB * 257 + 0] = (float)a;
    out[BB * 257 + 1] = (float)c;
  }
}

extern "C" void kernel_launch(void* const* d_in, const int* in_sizes, int n_in,
                              void* d_out, int out_size, void* d_ws, size_t ws_size,
                              hipStream_t stream) {
  const float* inputs = (const float*)d_in[0];
  const float* Wc  = (const float*)d_in[1];
  const float* bc  = (const float*)d_in[2];
  const float* Wq  = (const float*)d_in[3];
  const float* w_q = (const float*)d_in[4];
  const float* v   = (const float*)d_in[5];
  float* out = (float*)d_out;

  char* ws = (char*)d_ws;
  const size_t encBytes = (size_t)BB * HH * SS * 4;            // 64 MiB
  const size_t gF = (size_t)3 * BB * SS * QQ * 4;              // 135 MiB (float G)
  const size_t gH = (size_t)3 * BB * SS * QQ * 2;              // half G fallback
  bool useF = ws_size >= encBytes + gF + 4096;

  float* encT = (float*)ws;
  void* G = (void*)(ws + encBytes);
  size_t goff = encBytes + (useF ? gF : gH);
  goff = (goff + 1023) & ~(size_t)1023;
  double* lpb = (double*)(ws + goff);
  double* entb = lpb + BB;

  dim3 gA1(8, BB);
  k_enc<<<gA1, 256, 0, stream>>>(inputs, Wc, bc, encT);
  dim3 gA2(6, BB, 3);
  if (useF) {
    k_G<float><<<gA2, 256, 0, stream>>>(inputs, Wq, (float*)G);
    k_scan<float><<<BB, 512, 0, stream>>>(w_q, v, encT, (const float*)G, out, lpb, entb);
  } else {
    k_G<__half><<<gA2, 256, 0, stream>>>(inputs, Wq, (__half*)G);
    k_scan<__half><<<BB, 512, 0, stream>>>(w_q, v, encT, (const __half*)G, out, lpb, entb);
  }
  k_final<<<1, 64, 0, stream>>>(lpb, entb, out);
}

// Round 2
// 17550.536 us; speedup vs baseline: 1.6111x; 1.6111x over previous
//
#include <hip/hip_runtime.h>
#include <hip/hip_fp16.h>
#include <stdint.h>

#define BB 128
#define SS 256
#define HH 512
#define QQ 360

// ---------------- Threefry-2x32 (JAX semantics) ----------------
struct TF2 { uint32_t a, b; };

__host__ __device__ constexpr uint32_t rotl32(uint32_t x, int d) {
  return (x << d) | (x >> (32 - d));
}

__host__ __device__ constexpr TF2 threefry(uint32_t k0, uint32_t k1,
                                           uint32_t x0, uint32_t x1) {
  uint32_t ks[3] = {k0, k1, k0 ^ k1 ^ 0x1BD11BDAu};
  x0 += ks[0]; x1 += ks[1];
  const int R0[4] = {13, 15, 26, 6};
  const int R1[4] = {17, 29, 16, 24};
  for (int g = 0; g < 5; ++g) {
    const int* r = (g & 1) ? R1 : R0;
    for (int i = 0; i < 4; ++i) { x0 += x1; x1 = rotl32(x1, r[i]); x1 ^= x0; }
    x0 += ks[(g + 1) % 3];
    x1 += ks[(g + 2) % 3] + (uint32_t)(g + 1);
  }
  return TF2{x0, x1};
}

struct KeyTab { uint32_t sk[256][2]; };
constexpr KeyTab make_keys() {
  KeyTab K{};
  uint32_t k0 = 0u, k1 = 1u;
  for (int t = 0; t < 256; ++t) {
    TF2 nk = threefry(k0, k1, 0u, 0u);
    TF2 sk = threefry(k0, k1, 0u, 1u);
    K.sk[t][0] = sk.a; K.sk[t][1] = sk.b;
    k0 = nk.a; k1 = nk.b;
  }
  return K;
}
__constant__ KeyTab c_keys = make_keys();

// ---------------- fast math helpers ----------------
__device__ __forceinline__ float frcp(float x) {
#if __has_builtin(__builtin_amdgcn_rcpf)
  return __builtin_amdgcn_rcpf(x);
#else
  return 1.0f / x;
#endif
}
// tanh(x) = 1 - 2/(exp(2x)+1); exact at +-inf saturation, ~1e-6 rel err.
__device__ __forceinline__ float fast_tanh(float x) {
  float e = __expf(2.0f * x);
  return 1.0f - 2.0f * frcp(e + 1.0f);
}

// ---------------- Phase A1: encH[b][h][s] = half( (inputs @ Wc + bc)^T ) ----------------
__global__ __launch_bounds__(256) void k_enc(const float* __restrict__ inputs,
                                             const float* __restrict__ Wc,
                                             const float* __restrict__ bc,
                                             __half* __restrict__ encH) {
  const int ht = blockIdx.x;
  const int b  = blockIdx.y;
  const int tid = threadIdx.x;
  const int ts = tid & 63, th = tid >> 6;
  __shared__ float Xs[32 * 260];
  __shared__ float Ws[32 * 64];
  float acc[16][4];
#pragma unroll
  for (int i = 0; i < 16; ++i)
#pragma unroll
    for (int j = 0; j < 4; ++j) acc[i][j] = 0.f;

  const float* Arow = inputs + ((size_t)b * SS + tid) * HH;
  for (int kk = 0; kk < HH; kk += 32) {
    const float4* ip = (const float4*)(Arow + kk);
#pragma unroll
    for (int e = 0; e < 8; ++e) {
      float4 w = ip[e];
      Xs[(e * 4 + 0) * 260 + tid] = w.x;
      Xs[(e * 4 + 1) * 260 + tid] = w.y;
      Xs[(e * 4 + 2) * 260 + tid] = w.z;
      Xs[(e * 4 + 3) * 260 + tid] = w.w;
    }
    {
      int kw = tid >> 3, hw = (tid & 7) * 8;
      const float4* wp = (const float4*)(Wc + (size_t)(kk + kw) * HH + ht * 64 + hw);
      float4 w0 = wp[0], w1 = wp[1];
      float* d = Ws + kw * 64 + hw;
      ((float4*)d)[0] = w0; ((float4*)d)[1] = w1;
    }
    __syncthreads();
#pragma unroll 8
    for (int k = 0; k < 32; ++k) {
      float xr[4];
#pragma unroll
      for (int j = 0; j < 4; ++j) xr[j] = Xs[k * 260 + ts + 64 * j];
      const float4* wr4 = (const float4*)(Ws + k * 64 + th * 16);
#pragma unroll
      for (int i4 = 0; i4 < 4; ++i4) {
        float4 w = wr4[i4];
        float wv[4] = {w.x, w.y, w.z, w.w};
#pragma unroll
        for (int c = 0; c < 4; ++c)
#pragma unroll
          for (int j = 0; j < 4; ++j) acc[i4 * 4 + c][j] += wv[c] * xr[j];
      }
    }
    __syncthreads();
  }
#pragma unroll
  for (int i = 0; i < 16; ++i) {
    int h = ht * 64 + th * 16 + i;
    float bcv = bc[h];
    __half* orow = encH + (size_t)b * (HH * SS) + (size_t)h * SS + ts;
#pragma unroll
    for (int j = 0; j < 4; ++j) orow[64 * j] = __float2half(acc[i][j] + bcv);
  }
}

// ---------------- Phase A2: G[k][b][j][q] = half( inputs[b,j,:] @ Wq[k] ) ----------------
__global__ __launch_bounds__(256) void k_G(const float* __restrict__ inputs,
                                           const float* __restrict__ Wq,
                                           __half* __restrict__ G) {
  const int qt = blockIdx.x;
  const int b  = blockIdx.y;
  const int k  = blockIdx.z;
  const int tid = threadIdx.x;
  const int ql = tid & 63, tj = tid >> 6;
  __shared__ float Xs[32 * 260];
  __shared__ float Ws[32 * 64];
  float acc[64];
#pragma unroll
  for (int j = 0; j < 64; ++j) acc[j] = 0.f;
  const int q = qt * 64 + ql;
  const float* Arow = inputs + ((size_t)b * SS + tid) * HH;
  const float* Wqk = Wq + (size_t)k * HH * QQ;
  for (int kk = 0; kk < HH; kk += 32) {
    const float4* ip = (const float4*)(Arow + kk);
#pragma unroll
    for (int e = 0; e < 8; ++e) {
      float4 w = ip[e];
      Xs[(e * 4 + 0) * 260 + tid] = w.x;
      Xs[(e * 4 + 1) * 260 + tid] = w.y;
      Xs[(e * 4 + 2) * 260 + tid] = w.z;
      Xs[(e * 4 + 3) * 260 + tid] = w.w;
    }
    {
      int hh = tid >> 3, qw = (tid & 7) * 8;
      const float* src = Wqk + (size_t)(kk + hh) * QQ;
      float* d = Ws + hh * 64 + qw;
#pragma unroll
      for (int e = 0; e < 8; ++e) {
        int qg = qt * 64 + qw + e;
        d[e] = (qg < QQ) ? src[qg] : 0.f;
      }
    }
    __syncthreads();
#pragma unroll 4
    for (int k2 = 0; k2 < 32; ++k2) {
      float wr = Ws[k2 * 64 + ql];
      const float4* xp = (const float4*)(Xs + k2 * 260 + tj * 64);
#pragma unroll
      for (int j4 = 0; j4 < 16; ++j4) {
        float4 x = xp[j4];
        acc[j4 * 4 + 0] += wr * x.x;
        acc[j4 * 4 + 1] += wr * x.y;
        acc[j4 * 4 + 2] += wr * x.z;
        acc[j4 * 4 + 3] += wr * x.w;
      }
    }
    __syncthreads();
  }
  if (q < QQ) {
    __half* gb = G + (((size_t)k * BB + b) * SS + tj * 64) * QQ + q;
#pragma unroll
    for (int j = 0; j < 64; ++j) gb[(size_t)j * QQ] = __float2half(acc[j]);
  }
}

// ---------------- Main scan: 1024 threads/block, block = batch ----------------
__global__ __launch_bounds__(1024) void k_scan(
    const float* __restrict__ w_q, const float* __restrict__ v,
    const __half* __restrict__ encH, const __half* __restrict__ G,
    float* __restrict__ out, double* __restrict__ lpb, double* __restrict__ entb) {
  const int b = blockIdx.x;
  const int tid = (int)threadIdx.x;
  const int lane = tid & 63;
  const int wid = tid >> 6;            // 16 waves
  const int hl = lane >> 5;            // half-wave: which of the 2 h rows
  const int sl = lane & 31;
  const int sbase = sl * 8;            // 8 consecutive s per lane

  __shared__ float q_s[QQ];
  __shared__ float eq2[2][HH];
  __shared__ float v_s[HH];
  __shared__ float part[16][SS];
  __shared__ float mask_s[SS];
  __shared__ int hist[3];

  if (tid < HH) v_s[tid] = v[tid];
  if (tid < SS) mask_s[tid] = 0.f;
  if (tid < 3) hist[tid] = -1;
  __syncthreads();

  double lp_acc = 0.0, ent_acc = 0.0;
  int first_idx = 0;

  // wave wid owns h in [wid*32, wid*32+32); iteration it covers h = wid*32 + 2*it + hl
  const __half* encW = encH + (size_t)b * (HH * SS) + (size_t)(wid * 32 + hl) * SS + sbase;

  for (int t = 0; t < SS; ++t) {
    // ---- prefetch first half of enc tiles (in flight across P1+P2) ----
    float4 bufA[4], bufB[4];
#pragma unroll
    for (int i = 0; i < 4; ++i) bufA[i] = *(const float4*)(encW + (size_t)(2 * i) * SS);
#pragma unroll
    for (int i = 0; i < 4; ++i) bufB[i] = *(const float4*)(encW + (size_t)(2 * (i + 4)) * SS);

    // ---- P1: query[q] = relu(sum_k G[k][b][hist[k]][q]) ----
    if (tid < QQ) {
      float s3 = 0.f;
#pragma unroll
      for (int k = 0; k < 3; ++k) {
        int j = hist[k];
        if (j >= 0) s3 += __half2float(G[(((size_t)k * BB + b) * SS + j) * QQ + tid]);
      }
      q_s[tid] = fmaxf(s3, 0.f);
    }
    __syncthreads();

    // ---- P2: eq[h] partials: 2 threads per h, 180 q each ----
    {
      int h2 = tid & (HH - 1);
      int half = tid >> 9;
      int q0 = half * 180;
      const float* wp = w_q + (size_t)q0 * HH + h2;
      float a0 = 0.f, a1 = 0.f, a2 = 0.f, a3 = 0.f;
      for (int i = 0; i < 180; i += 4) {
        a0 = fmaf(q_s[q0 + i],     wp[(size_t)(i)     * HH], a0);
        a1 = fmaf(q_s[q0 + i + 1], wp[(size_t)(i + 1) * HH], a1);
        a2 = fmaf(q_s[q0 + i + 2], wp[(size_t)(i + 2) * HH], a2);
        a3 = fmaf(q_s[q0 + i + 3], wp[(size_t)(i + 3) * HH], a3);
      }
      eq2[half][h2] = (a0 + a1) + (a2 + a3);
    }
    __syncthreads();

    // ---- P3: partial scores; each lane: 8 s-values, wave covers 32 h ----
    float acc[8];
#pragma unroll
    for (int j = 0; j < 8; ++j) acc[j] = 0.f;

    auto consume = [&](const float4 (&buf)[4], int itbase) {
#pragma unroll
      for (int i = 0; i < 4; ++i) {
        int h = wid * 32 + (itbase + i) * 2 + hl;
        float eqv = eq2[0][h] + eq2[1][h];
        float vv = v_s[h];
        const __half2* hp = (const __half2*)&buf[i];
#pragma unroll
        for (int j = 0; j < 4; ++j) {
          float2 ef = __half22float2(hp[j]);
          acc[2 * j]     = fmaf(vv, fast_tanh(ef.x + eqv), acc[2 * j]);
          acc[2 * j + 1] = fmaf(vv, fast_tanh(ef.y + eqv), acc[2 * j + 1]);
        }
      }
    };

    consume(bufA, 0);
#pragma unroll
    for (int i = 0; i < 4; ++i) bufA[i] = *(const float4*)(encW + (size_t)(2 * (i + 8)) * SS);
    consume(bufB, 4);
#pragma unroll
    for (int i = 0; i < 4; ++i) bufB[i] = *(const float4*)(encW + (size_t)(2 * (i + 12)) * SS);
    consume(bufA, 8);
    consume(bufB, 12);

    // combine the two half-waves (same s, different h), write per-wave partials
#pragma unroll
    for (int j = 0; j < 8; ++j) acc[j] += __shfl_xor(acc[j], 32);
    if (hl == 0) {
#pragma unroll
      for (int j = 0; j < 8; ++j) part[wid][sbase + j] = acc[j];
    }
    __syncthreads();

    // ---- P4: single wave does logits, gumbel, argmax, lse, entropy ----
    if (tid < 64) {
      float msk[4];
      float zb = -3.0e38f, ml = -3.0e38f;
      int ib = 0;
#pragma unroll
      for (int j = 0; j < 4; ++j) {
        int s = lane + 64 * j;
        float sc = 0.f;
#pragma unroll
        for (int r = 0; r < 16; ++r) sc += part[r][s];
        float logit = 10.0f * fast_tanh(sc);
        float m = (mask_s[s] != 0.f) ? -1.0e8f : logit;
        msk[j] = m;
        TF2 o = threefry(c_keys.sk[t][0], c_keys.sk[t][1], 0u, (uint32_t)(b * SS + s));
        float fb = __uint_as_float((o.b >> 9) | 0x3f800000u) - 1.0f;
        fb = fmaxf(fb, 1.0e-12f);
        float g = -__logf(-__logf(fb));
        float z = m + g;
        if (z > zb) { zb = z; ib = s; }
        ml = fmaxf(ml, m);
      }
#pragma unroll
      for (int off = 32; off; off >>= 1) {
        float zo = __shfl_xor(zb, off);
        int io = __shfl_xor(ib, off);
        if (zo > zb || (zo == zb && io < ib)) { zb = zo; ib = io; }
        ml = fmaxf(ml, __shfl_xor(ml, off));
      }
      const int idx = ib;       // butterfly: all lanes agree
      const float MB = ml;
      float se = 0.f, sem = 0.f, matidx = -3.0e38f;
#pragma unroll
      for (int j = 0; j < 4; ++j) {
        float e = __expf(msk[j] - MB);
        se += e;
        sem += e * msk[j];
        if (lane + 64 * j == idx) matidx = msk[j];
      }
#pragma unroll
      for (int off = 32; off; off >>= 1) {
        se += __shfl_xor(se, off);
        sem += __shfl_xor(sem, off);
        matidx = fmaxf(matidx, __shfl_xor(matidx, off));
      }
      if (lane == (idx & 63)) mask_s[idx] = 1.0f;
      if (lane == 0) {
        float lse = MB + __logf(se);
        lp_acc += (double)(matidx - lse);
        ent_acc += (double)(lse - sem / se);
        out[b * 257 + t] = (float)idx;
        hist[0] = hist[1]; hist[1] = hist[2]; hist[2] = idx;
        if (t == 0) first_idx = idx;
      }
    }
    __syncthreads();
  }

  if (tid == 0) {
    out[b * 257 + 256] = (float)first_idx;
    lpb[b] = lp_acc;
    entb[b] = ent_acc;
  }
}

// ---------------- Final deterministic reduction ----------------
__global__ void k_final(const double* __restrict__ lpb,
                        const double* __restrict__ entb, float* __restrict__ out) {
  if (threadIdx.x == 0) {
    double a = 0.0, c = 0.0;
    for (int i = 0; i < BB; ++i) { a += lpb[i]; c += entb[i]; }
    out[BB * 257 + 0] = (float)a;
    out[BB * 257 + 1] = (float)c;
  }
}

extern "C" void kernel_launch(void* const* d_in, const int* in_sizes, int n_in,
                              void* d_out, int out_size, void* d_ws, size_t ws_size,
                              hipStream_t stream) {
  const float* inputs = (const float*)d_in[0];
  const float* Wc  = (const float*)d_in[1];
  const float* bc  = (const float*)d_in[2];
  const float* Wq  = (const float*)d_in[3];
  const float* w_q = (const float*)d_in[4];
  const float* v   = (const float*)d_in[5];
  float* out = (float*)d_out;

  char* ws = (char*)d_ws;
  const size_t encBytes = (size_t)BB * HH * SS * 2;      // 32 MiB fp16
  const size_t gBytes   = (size_t)3 * BB * SS * QQ * 2;  // 67.5 MiB fp16
  __half* encH = (__half*)ws;
  __half* G = (__half*)(ws + encBytes);
  size_t goff = (encBytes + gBytes + 1023) & ~(size_t)1023;
  double* lpb = (double*)(ws + goff);
  double* entb = lpb + BB;

  dim3 gA1(8, BB);
  k_enc<<<gA1, 256, 0, stream>>>(inputs, Wc, bc, encH);
  dim3 gA2(6, BB, 3);
  k_G<<<gA2, 256, 0, stream>>>(inputs, Wq, G);
  k_scan<<<BB, 1024, 0, stream>>>(w_q, v, encH, G, out, lpb, entb);
  k_final<<<1, 64, 0, stream>>>(lpb, entb, out);
}

// Round 3
// 11659.202 us; speedup vs baseline: 2.4251x; 1.5053x over previous
//
#include <hip/hip_runtime.h>
#include <hip/hip_fp16.h>
#include <stdint.h>

#define BB 128
#define SS 256
#define HH 512
#define QQ 360

// ---------------- Threefry-2x32 (JAX semantics) ----------------
struct TF2 { uint32_t a, b; };

__host__ __device__ constexpr uint32_t rotl32(uint32_t x, int d) {
  return (x << d) | (x >> (32 - d));
}

__host__ __device__ constexpr TF2 threefry(uint32_t k0, uint32_t k1,
                                           uint32_t x0, uint32_t x1) {
  uint32_t ks[3] = {k0, k1, k0 ^ k1 ^ 0x1BD11BDAu};
  x0 += ks[0]; x1 += ks[1];
  const int R0[4] = {13, 15, 26, 6};
  const int R1[4] = {17, 29, 16, 24};
  for (int g = 0; g < 5; ++g) {
    const int* r = (g & 1) ? R1 : R0;
    for (int i = 0; i < 4; ++i) { x0 += x1; x1 = rotl32(x1, r[i]); x1 ^= x0; }
    x0 += ks[(g + 1) % 3];
    x1 += ks[(g + 2) % 3] + (uint32_t)(g + 1);
  }
  return TF2{x0, x1};
}

struct KeyTab { uint32_t sk[256][2]; };
constexpr KeyTab make_keys() {
  KeyTab K{};
  uint32_t k0 = 0u, k1 = 1u;
  for (int t = 0; t < 256; ++t) {
    TF2 nk = threefry(k0, k1, 0u, 0u);
    TF2 sk = threefry(k0, k1, 0u, 1u);
    K.sk[t][0] = sk.a; K.sk[t][1] = sk.b;
    k0 = nk.a; k1 = nk.b;
  }
  return K;
}
__constant__ KeyTab c_keys = make_keys();

// ---------------- fast math helpers ----------------
__device__ __forceinline__ float frcp(float x) {
#if __has_builtin(__builtin_amdgcn_rcpf)
  return __builtin_amdgcn_rcpf(x);
#else
  return 1.0f / x;
#endif
}

// exp2-based tanh pipeline: tanh(x) = 1 - 2/(1 + 2^(C*x)) with C = 2*log2(e)
#if __has_builtin(__builtin_amdgcn_exp2f)
  #define EXP2F(x) __builtin_amdgcn_exp2f(x)
  #define CC 2.8853900817779268f
#else
  #define EXP2F(x) __expf(x)   /* e^(2x) form */
  #define CC 2.0f
#endif

#define ENC_SCALE 21.0f
#define ENC_INV (CC / ENC_SCALE)

__device__ __forceinline__ float fast_tanh(float x) {
  float e = __expf(2.0f * x);
  return 1.0f - 2.0f * frcp(e + 1.0f);
}

// ---------------- Phase A1: enc8[b][h][s] = int8( 21 * (inputs @ Wc + bc)^T ) ----------------
__global__ __launch_bounds__(256) void k_enc(const float* __restrict__ inputs,
                                             const float* __restrict__ Wc,
                                             const float* __restrict__ bc,
                                             int8_t* __restrict__ enc8) {
  const int ht = blockIdx.x;
  const int b  = blockIdx.y;
  const int tid = threadIdx.x;
  const int ts = tid & 63, th = tid >> 6;
  __shared__ float Xs[32 * 260];
  __shared__ float Ws[32 * 64];
  float acc[16][4];
#pragma unroll
  for (int i = 0; i < 16; ++i)
#pragma unroll
    for (int j = 0; j < 4; ++j) acc[i][j] = 0.f;

  const float* Arow = inputs + ((size_t)b * SS + tid) * HH;
  for (int kk = 0; kk < HH; kk += 32) {
    const float4* ip = (const float4*)(Arow + kk);
#pragma unroll
    for (int e = 0; e < 8; ++e) {
      float4 w = ip[e];
      Xs[(e * 4 + 0) * 260 + tid] = w.x;
      Xs[(e * 4 + 1) * 260 + tid] = w.y;
      Xs[(e * 4 + 2) * 260 + tid] = w.z;
      Xs[(e * 4 + 3) * 260 + tid] = w.w;
    }
    {
      int kw = tid >> 3, hw = (tid & 7) * 8;
      const float4* wp = (const float4*)(Wc + (size_t)(kk + kw) * HH + ht * 64 + hw);
      float4 w0 = wp[0], w1 = wp[1];
      float* d = Ws + kw * 64 + hw;
      ((float4*)d)[0] = w0; ((float4*)d)[1] = w1;
    }
    __syncthreads();
#pragma unroll 8
    for (int k = 0; k < 32; ++k) {
      float xr[4];
#pragma unroll
      for (int j = 0; j < 4; ++j) xr[j] = Xs[k * 260 + ts + 64 * j];
      const float4* wr4 = (const float4*)(Ws + k * 64 + th * 16);
#pragma unroll
      for (int i4 = 0; i4 < 4; ++i4) {
        float4 w = wr4[i4];
        float wv[4] = {w.x, w.y, w.z, w.w};
#pragma unroll
        for (int c = 0; c < 4; ++c)
#pragma unroll
          for (int j = 0; j < 4; ++j) acc[i4 * 4 + c][j] += wv[c] * xr[j];
      }
    }
    __syncthreads();
  }
#pragma unroll
  for (int i = 0; i < 16; ++i) {
    int h = ht * 64 + th * 16 + i;
    float bcv = bc[h];
    int8_t* orow = enc8 + (size_t)b * (HH * SS) + (size_t)h * SS + ts;
#pragma unroll
    for (int j = 0; j < 4; ++j) {
      float q = rintf(fminf(fmaxf((acc[i][j] + bcv) * ENC_SCALE, -127.f), 127.f));
      orow[64 * j] = (int8_t)(int)q;
    }
  }
}

// ---------------- Phase A2: G[k][b][j][q] = half( inputs[b,j,:] @ Wq[k] ) ----------------
__global__ __launch_bounds__(256) void k_G(const float* __restrict__ inputs,
                                           const float* __restrict__ Wq,
                                           __half* __restrict__ G) {
  const int qt = blockIdx.x;
  const int b  = blockIdx.y;
  const int k  = blockIdx.z;
  const int tid = threadIdx.x;
  const int ql = tid & 63, tj = tid >> 6;
  __shared__ float Xs[32 * 260];
  __shared__ float Ws[32 * 64];
  float acc[64];
#pragma unroll
  for (int j = 0; j < 64; ++j) acc[j] = 0.f;
  const int q = qt * 64 + ql;
  const float* Arow = inputs + ((size_t)b * SS + tid) * HH;
  const float* Wqk = Wq + (size_t)k * HH * QQ;
  for (int kk = 0; kk < HH; kk += 32) {
    const float4* ip = (const float4*)(Arow + kk);
#pragma unroll
    for (int e = 0; e < 8; ++e) {
      float4 w = ip[e];
      Xs[(e * 4 + 0) * 260 + tid] = w.x;
      Xs[(e * 4 + 1) * 260 + tid] = w.y;
      Xs[(e * 4 + 2) * 260 + tid] = w.z;
      Xs[(e * 4 + 3) * 260 + tid] = w.w;
    }
    {
      int hh = tid >> 3, qw = (tid & 7) * 8;
      const float* src = Wqk + (size_t)(kk + hh) * QQ;
      float* d = Ws + hh * 64 + qw;
#pragma unroll
      for (int e = 0; e < 8; ++e) {
        int qg = qt * 64 + qw + e;
        d[e] = (qg < QQ) ? src[qg] : 0.f;
      }
    }
    __syncthreads();
#pragma unroll 4
    for (int k2 = 0; k2 < 32; ++k2) {
      float wr = Ws[k2 * 64 + ql];
      const float4* xp = (const float4*)(Xs + k2 * 260 + tj * 64);
#pragma unroll
      for (int j4 = 0; j4 < 16; ++j4) {
        float4 x = xp[j4];
        acc[j4 * 4 + 0] += wr * x.x;
        acc[j4 * 4 + 1] += wr * x.y;
        acc[j4 * 4 + 2] += wr * x.z;
        acc[j4 * 4 + 3] += wr * x.w;
      }
    }
    __syncthreads();
  }
  if (q < QQ) {
    __half* gb = G + (((size_t)k * BB + b) * SS + tj * 64) * QQ + q;
#pragma unroll
    for (int j = 0; j < 64; ++j) gb[(size_t)j * QQ] = __float2half(acc[j]);
  }
}

// ---------------- w_q fp32 -> fp16 ----------------
__global__ __launch_bounds__(1024) void k_wq16(const float* __restrict__ w_q,
                                               __half* __restrict__ w16) {
  int t = blockIdx.x * 1024 + threadIdx.x;
  if (t < QQ * HH) w16[t] = __float2half(w_q[t]);
}

// ---------------- Main scan: 1024 threads/block, block = batch ----------------
__global__ __launch_bounds__(1024) void k_scan(
    const __half* __restrict__ w16, const float* __restrict__ v,
    const int8_t* __restrict__ enc8, const __half* __restrict__ G,
    float* __restrict__ out, double* __restrict__ lpb, double* __restrict__ entb) {
  const int b = blockIdx.x;
  const int tid = (int)threadIdx.x;
  const int lane = tid & 63;
  const int wid = tid >> 6;            // 16 waves
  const int hl = lane >> 5;            // which of the 2 h rows per iter
  const int sl = lane & 31;
  const int sbase = sl * 8;            // 8 consecutive s per lane

  __shared__ float eqp4[4][HH];        // P2 partials
  __shared__ float eqC_s[HH];          // CC * eq[h]
  __shared__ float m2v_s[HH];          // -2 * v[h]
  __shared__ float q_s[QQ];
  __shared__ float part[16][SS];
  __shared__ float mask_s[SS];
  __shared__ int hist[3];
  __shared__ float Vtot_s;

  // ---- init ----
  if (tid < HH) { float vv = v[tid]; m2v_s[tid] = -2.0f * vv; ((float*)part)[tid] = vv; }
  if (tid < SS) mask_s[tid] = 0.f;
  if (tid < 3) hist[tid] = -1;
  __syncthreads();
  if (tid == 0) {
    float s = 0.f;
    for (int i = 0; i < HH; ++i) s += ((float*)part)[i];
    Vtot_s = s;
  }
  __syncthreads();

  // ---- load this lane's enc slice into registers (step-invariant!) ----
  // iter i covers rows h = wid*32 + 2*i + hl, this lane's s = sbase..sbase+7
  uint2 enc_r[16];
  {
    const int8_t* encW = enc8 + (size_t)b * (HH * SS) + (size_t)(wid * 32 + hl) * SS + sbase;
#pragma unroll
    for (int i = 0; i < 16; ++i)
      enc_r[i] = *(const uint2*)(encW + (size_t)(2 * i) * SS);
  }

  double lp_acc = 0.0, ent_acc = 0.0;
  int first_idx = 0;
  const float Vtot = Vtot_s;

  for (int t = 0; t < SS; ++t) {
    // ---- P1: query[q] = relu(sum_k G[k][b][hist[k]][q]) ----
    if (tid < QQ) {
      float s3 = 0.f;
#pragma unroll
      for (int k = 0; k < 3; ++k) {
        int j = hist[k];
        if (j >= 0) s3 += __half2float(G[(((size_t)k * BB + b) * SS + j) * QQ + tid]);
      }
      q_s[tid] = fmaxf(s3, 0.f);
    }
    __syncthreads();

    // ---- P2: eq partials; thread covers h pair (2*hp, 2*hp+1), 90 q's ----
    {
      const int hp = tid & 255, qq = tid >> 8;
      const int q0 = qq * 90;
      const __half2* wbase = (const __half2*)w16 + hp;
      float a0 = 0.f, a1 = 0.f;
#pragma unroll 6
      for (int i = 0; i < 90; ++i) {
        float2 f2 = __half22float2(wbase[(size_t)(q0 + i) * (HH / 2)]);
        float qv = q_s[q0 + i];
        a0 = fmaf(qv, f2.x, a0);
        a1 = fmaf(qv, f2.y, a1);
      }
      eqp4[qq][2 * hp]     = a0;
      eqp4[qq][2 * hp + 1] = a1;
    }
    __syncthreads();

    // ---- reduce partials -> eqC = CC * eq[h] ----
    if (tid < HH) {
      float s = (eqp4[0][tid] + eqp4[1][tid]) + (eqp4[2][tid] + eqp4[3][tid]);
      eqC_s[tid] = CC * s;
    }
    __syncthreads();

    // ---- P3: pure-VALU scores from register-resident int8 enc ----
    {
      float acc[8];
#pragma unroll
      for (int j = 0; j < 8; ++j) acc[j] = 0.f;
#pragma unroll
      for (int i = 0; i < 16; ++i) {
        const int h = wid * 32 + 2 * i + hl;
        const float eqC = eqC_s[h];
        const float mv = m2v_s[h];
        const uint32_t w0 = enc_r[i].x, w1 = enc_r[i].y;
#pragma unroll
        for (int k = 0; k < 4; ++k) {
          {
            float f = (float)(int)(int8_t)(w0 >> (8 * k));
            float e = EXP2F(fmaf(f, ENC_INV, eqC));
            acc[k] = fmaf(mv, frcp(e + 1.0f), acc[k]);
          }
          {
            float f = (float)(int)(int8_t)(w1 >> (8 * k));
            float e = EXP2F(fmaf(f, ENC_INV, eqC));
            acc[4 + k] = fmaf(mv, frcp(e + 1.0f), acc[4 + k]);
          }
        }
      }
      // combine the two half-waves (same s, different h rows)
#pragma unroll
      for (int j = 0; j < 8; ++j) acc[j] += __shfl_xor(acc[j], 32);
      if (hl == 0) {
#pragma unroll
        for (int j = 0; j < 8; ++j) part[wid][sbase + j] = acc[j];
      }
    }
    __syncthreads();

    // ---- P4: single wave: logits, gumbel, argmax, lse, entropy ----
    if (tid < 64) {
      float msk[4];
      float zb = -3.0e38f, ml = -3.0e38f;
      int ib = 0;
#pragma unroll
      for (int j = 0; j < 4; ++j) {
        int s = lane + 64 * j;
        float sc = Vtot;
#pragma unroll
        for (int r = 0; r < 16; ++r) sc += part[r][s];
        float logit = 10.0f * fast_tanh(sc);
        float m = (mask_s[s] != 0.f) ? -1.0e8f : logit;
        msk[j] = m;
        TF2 o = threefry(c_keys.sk[t][0], c_keys.sk[t][1], 0u, (uint32_t)(b * SS + s));
        float fb = __uint_as_float((o.b >> 9) | 0x3f800000u) - 1.0f;
        fb = fmaxf(fb, 1.0e-12f);
        float g = -__logf(-__logf(fb));
        float z = m + g;
        if (z > zb) { zb = z; ib = s; }
        ml = fmaxf(ml, m);
      }
#pragma unroll
      for (int off = 32; off; off >>= 1) {
        float zo = __shfl_xor(zb, off);
        int io = __shfl_xor(ib, off);
        if (zo > zb || (zo == zb && io < ib)) { zb = zo; ib = io; }
        ml = fmaxf(ml, __shfl_xor(ml, off));
      }
      const int idx = ib;
      const float MB = ml;
      float se = 0.f, sem = 0.f, matidx = -3.0e38f;
#pragma unroll
      for (int j = 0; j < 4; ++j) {
        float e = __expf(msk[j] - MB);
        se += e;
        sem += e * msk[j];
        if (lane + 64 * j == idx) matidx = msk[j];
      }
#pragma unroll
      for (int off = 32; off; off >>= 1) {
        se += __shfl_xor(se, off);
        sem += __shfl_xor(sem, off);
        matidx = fmaxf(matidx, __shfl_xor(matidx, off));
      }
      if (lane == (idx & 63)) mask_s[idx] = 1.0f;
      if (lane == 0) {
        float lse = MB + __logf(se);
        lp_acc += (double)(matidx - lse);
        ent_acc += (double)(lse - sem / se);
        out[b * 257 + t] = (float)idx;
        hist[0] = hist[1]; hist[1] = hist[2]; hist[2] = idx;
        if (t == 0) first_idx = idx;
      }
    }
    __syncthreads();
  }

  if (tid == 0) {
    out[b * 257 + 256] = (float)first_idx;
    lpb[b] = lp_acc;
    entb[b] = ent_acc;
  }
}

// ---------------- Final deterministic reduction ----------------
__global__ void k_final(const double* __restrict__ lpb,
                        const double* __restrict__ entb, float* __restrict__ out) {
  if (threadIdx.x == 0) {
    double a = 0.0, c = 0.0;
    for (int i = 0; i < BB; ++i) { a += lpb[i]; c += entb[i]; }
    out[BB * 257 + 0] = (float)a;
    out[BB * 257 + 1] = (float)c;
  }
}

extern "C" void kernel_launch(void* const* d_in, const int* in_sizes, int n_in,
                              void* d_out, int out_size, void* d_ws, size_t ws_size,
                              hipStream_t stream) {
  const float* inputs = (const float*)d_in[0];
  const float* Wc  = (const float*)d_in[1];
  const float* bc  = (const float*)d_in[2];
  const float* Wq  = (const float*)d_in[3];
  const float* w_q = (const float*)d_in[4];
  const float* v   = (const float*)d_in[5];
  float* out = (float*)d_out;

  char* ws = (char*)d_ws;
  const size_t encBytes = (size_t)BB * HH * SS;            // 16.8 MB int8
  const size_t gBytes   = (size_t)3 * BB * SS * QQ * 2;    // 70.8 MB fp16
  const size_t wqBytes  = (size_t)QQ * HH * 2;             // 369 KB fp16
  int8_t* enc8 = (int8_t*)ws;
  __half* G   = (__half*)(ws + encBytes);
  __half* w16 = (__half*)(ws + encBytes + gBytes);
  size_t goff = (encBytes + gBytes + wqBytes + 1023) & ~(size_t)1023;
  double* lpb = (double*)(ws + goff);
  double* entb = lpb + BB;

  dim3 gA1(8, BB);
  k_enc<<<gA1, 256, 0, stream>>>(inputs, Wc, bc, enc8);
  dim3 gA2(6, BB, 3);
  k_G<<<gA2, 256, 0, stream>>>(inputs, Wq, G);
  k_wq16<<<180, 1024, 0, stream>>>(w_q, w16);
  k_scan<<<BB, 1024, 0, stream>>>(w16, v, enc8, G, out, lpb, entb);
  k_final<<<1, 64, 0, stream>>>(lpb, entb, out);
}

// Round 4
// 5395.174 us; speedup vs baseline: 5.2408x; 2.1610x over previous
//
#include <hip/hip_runtime.h>
#include <hip/hip_fp16.h>
#include <stdint.h>

#define BB 128
#define SS 256
#define HH 512
#define QQ 360

// ---------------- Threefry-2x32 (JAX semantics) ----------------
struct TF2 { uint32_t a, b; };

__host__ __device__ constexpr uint32_t rotl32(uint32_t x, int d) {
  return (x << d) | (x >> (32 - d));
}

__host__ __device__ constexpr TF2 threefry(uint32_t k0, uint32_t k1,
                                           uint32_t x0, uint32_t x1) {
  uint32_t ks[3] = {k0, k1, k0 ^ k1 ^ 0x1BD11BDAu};
  x0 += ks[0]; x1 += ks[1];
  const int R0[4] = {13, 15, 26, 6};
  const int R1[4] = {17, 29, 16, 24};
  for (int g = 0; g < 5; ++g) {
    const int* r = (g & 1) ? R1 : R0;
    for (int i = 0; i < 4; ++i) { x0 += x1; x1 = rotl32(x1, r[i]); x1 ^= x0; }
    x0 += ks[(g + 1) % 3];
    x1 += ks[(g + 2) % 3] + (uint32_t)(g + 1);
  }
  return TF2{x0, x1};
}

struct KeyTab { uint32_t sk[256][2]; };
constexpr KeyTab make_keys() {
  KeyTab K{};
  uint32_t k0 = 0u, k1 = 1u;
  for (int t = 0; t < 256; ++t) {
    TF2 nk = threefry(k0, k1, 0u, 0u);
    TF2 sk = threefry(k0, k1, 0u, 1u);
    K.sk[t][0] = sk.a; K.sk[t][1] = sk.b;
    k0 = nk.a; k1 = nk.b;
  }
  return K;
}
__constant__ KeyTab c_keys = make_keys();

// ---------------- fast math helpers ----------------
__device__ __forceinline__ float frcp(float x) {
#if __has_builtin(__builtin_amdgcn_rcpf)
  return __builtin_amdgcn_rcpf(x);
#else
  return 1.0f / x;
#endif
}

#if __has_builtin(__builtin_amdgcn_exp2f)
  #define EXP2F(x) __builtin_amdgcn_exp2f(x)
  #define CC 2.8853900817779268f
#else
  #define EXP2F(x) __expf(x)
  #define CC 2.0f
#endif

#define ENC_SCALE 21.0f
#define ENC_INV (CC / ENC_SCALE)

__device__ __forceinline__ float fast_tanh(float x) {
  float e = __expf(2.0f * x);
  return 1.0f - 2.0f * frcp(e + 1.0f);
}

// ---------------- Phase A1: enc8[b][h][s] = int8( 21 * (inputs @ Wc + bc)^T ) ----------------
__global__ __launch_bounds__(256) void k_enc(const float* __restrict__ inputs,
                                             const float* __restrict__ Wc,
                                             const float* __restrict__ bc,
                                             int8_t* __restrict__ enc8) {
  const int ht = blockIdx.x;
  const int b  = blockIdx.y;
  const int tid = threadIdx.x;
  const int ts = tid & 63, th = tid >> 6;
  __shared__ float Xs[32 * 260];
  __shared__ float Ws[32 * 64];
  float acc[16][4];
#pragma unroll
  for (int i = 0; i < 16; ++i)
#pragma unroll
    for (int j = 0; j < 4; ++j) acc[i][j] = 0.f;

  const float* Arow = inputs + ((size_t)b * SS + tid) * HH;
  for (int kk = 0; kk < HH; kk += 32) {
    const float4* ip = (const float4*)(Arow + kk);
#pragma unroll
    for (int e = 0; e < 8; ++e) {
      float4 w = ip[e];
      Xs[(e * 4 + 0) * 260 + tid] = w.x;
      Xs[(e * 4 + 1) * 260 + tid] = w.y;
      Xs[(e * 4 + 2) * 260 + tid] = w.z;
      Xs[(e * 4 + 3) * 260 + tid] = w.w;
    }
    {
      int kw = tid >> 3, hw = (tid & 7) * 8;
      const float4* wp = (const float4*)(Wc + (size_t)(kk + kw) * HH + ht * 64 + hw);
      float4 w0 = wp[0], w1 = wp[1];
      float* d = Ws + kw * 64 + hw;
      ((float4*)d)[0] = w0; ((float4*)d)[1] = w1;
    }
    __syncthreads();
#pragma unroll 8
    for (int k = 0; k < 32; ++k) {
      float xr[4];
#pragma unroll
      for (int j = 0; j < 4; ++j) xr[j] = Xs[k * 260 + ts + 64 * j];
      const float4* wr4 = (const float4*)(Ws + k * 64 + th * 16);
#pragma unroll
      for (int i4 = 0; i4 < 4; ++i4) {
        float4 w = wr4[i4];
        float wv[4] = {w.x, w.y, w.z, w.w};
#pragma unroll
        for (int c = 0; c < 4; ++c)
#pragma unroll
          for (int j = 0; j < 4; ++j) acc[i4 * 4 + c][j] += wv[c] * xr[j];
      }
    }
    __syncthreads();
  }
#pragma unroll
  for (int i = 0; i < 16; ++i) {
    int h = ht * 64 + th * 16 + i;
    float bcv = bc[h];
    int8_t* orow = enc8 + (size_t)b * (HH * SS) + (size_t)h * SS + ts;
#pragma unroll
    for (int j = 0; j < 4; ++j) {
      float q = rintf(fminf(fmaxf((acc[i][j] + bcv) * ENC_SCALE, -127.f), 127.f));
      orow[64 * j] = (int8_t)(int)q;
    }
  }
}

// ---------------- Phase A2: G[b][j][k][q] = half( inputs[b,j,:] @ Wq[k] ) ----------------
__global__ __launch_bounds__(256) void k_G(const float* __restrict__ inputs,
                                           const float* __restrict__ Wq,
                                           __half* __restrict__ G) {
  const int qt = blockIdx.x;
  const int b  = blockIdx.y;
  const int k  = blockIdx.z;
  const int tid = threadIdx.x;
  const int ql = tid & 63, tj = tid >> 6;
  __shared__ float Xs[32 * 260];
  __shared__ float Ws[32 * 64];
  float acc[64];
#pragma unroll
  for (int j = 0; j < 64; ++j) acc[j] = 0.f;
  const int q = qt * 64 + ql;
  const float* Arow = inputs + ((size_t)b * SS + tid) * HH;
  const float* Wqk = Wq + (size_t)k * HH * QQ;
  for (int kk = 0; kk < HH; kk += 32) {
    const float4* ip = (const float4*)(Arow + kk);
#pragma unroll
    for (int e = 0; e < 8; ++e) {
      float4 w = ip[e];
      Xs[(e * 4 + 0) * 260 + tid] = w.x;
      Xs[(e * 4 + 1) * 260 + tid] = w.y;
      Xs[(e * 4 + 2) * 260 + tid] = w.z;
      Xs[(e * 4 + 3) * 260 + tid] = w.w;
    }
    {
      int hh = tid >> 3, qw = (tid & 7) * 8;
      const float* src = Wqk + (size_t)(kk + hh) * QQ;
      float* d = Ws + hh * 64 + qw;
#pragma unroll
      for (int e = 0; e < 8; ++e) {
        int qg = qt * 64 + qw + e;
        d[e] = (qg < QQ) ? src[qg] : 0.f;
      }
    }
    __syncthreads();
#pragma unroll 4
    for (int k2 = 0; k2 < 32; ++k2) {
      float wr = Ws[k2 * 64 + ql];
      const float4* xp = (const float4*)(Xs + k2 * 260 + tj * 64);
#pragma unroll
      for (int j4 = 0; j4 < 16; ++j4) {
        float4 x = xp[j4];
        acc[j4 * 4 + 0] += wr * x.x;
        acc[j4 * 4 + 1] += wr * x.y;
        acc[j4 * 4 + 2] += wr * x.z;
        acc[j4 * 4 + 3] += wr * x.w;
      }
    }
    __syncthreads();
  }
  if (q < QQ) {
#pragma unroll
    for (int j = 0; j < 64; ++j) {
      size_t jg = (size_t)b * SS + (tj * 64 + j);
      G[(jg * 3 + k) * QQ + q] = __float2half(acc[j]);
    }
  }
}

// ---------------- w_q fp32 -> fp16 ----------------
__global__ __launch_bounds__(1024) void k_wq16(const float* __restrict__ w_q,
                                               __half* __restrict__ w16) {
  int t = blockIdx.x * 1024 + threadIdx.x;
  if (t < QQ * HH) w16[t] = __float2half(w_q[t]);
}

// ---------------- Main scan ----------------
__global__ __launch_bounds__(1024) void k_scan(
    const __half* __restrict__ w16, const float* __restrict__ v,
    const int8_t* __restrict__ enc8, const __half* __restrict__ G,
    float* __restrict__ out, double* __restrict__ lpb, double* __restrict__ entb) {
  const int b = blockIdx.x;
  const int tid = (int)threadIdx.x;
  const int lane = tid & 63;
  const int wid = tid >> 6;            // 16 waves
  // P2 geometry: lane = q_sub*8 + hq
  const int q_sub = lane >> 3;         // 0..7 (45 q's each)
  const int hq = lane & 7;             // 0..7 (4 h's each)
  // P3 geometry
  const int hl = lane >> 5;            // 0..1
  const int sl = lane & 31;
  const int sbase = sl * 8;

  __shared__ float2 evq[HH];           // .x = CC*eq[h] (per step), .y = -2*v[h]
  __shared__ float q_s[QQ];            // current query (relu'd)
  __shared__ float q12_s[QQ];          // prefetched G0+G1 for next step
  __shared__ float part[16][SS];
  __shared__ float m_s[SS];
  __shared__ float mask_s[SS];
  __shared__ float4 wred[4];
  __shared__ int hist[3];
  __shared__ float Vtot_s;

  // ---- init ----
  if (tid < HH) evq[tid] = make_float2(0.f, -2.0f * v[tid]);
  if (tid < SS) mask_s[tid] = 0.f;
  if (tid < QQ) { q_s[tid] = 0.f; q12_s[tid] = 0.f; }
  if (tid < 3) hist[tid] = -1;
  if (tid < 64) {
    float s = 0.f;
#pragma unroll
    for (int j = 0; j < 8; ++j) s += v[tid + 64 * j];
#pragma unroll
    for (int off = 32; off; off >>= 1) s += __shfl_xor(s, off);
    if (tid == 0) Vtot_s = s;
  }
  __syncthreads();
  const float Vtot = Vtot_s;

  // ---- register-resident int8 enc slice ----
  uint2 enc_r[16];
  {
    const int8_t* encW = enc8 + (size_t)b * (HH * SS) + (size_t)(wid * 32 + hl) * SS + sbase;
#pragma unroll
    for (int i = 0; i < 16; ++i)
      enc_r[i] = *(const uint2*)(encW + (size_t)(2 * i) * SS);
  }

  const __half* Gb = G + (size_t)b * SS * 3 * QQ;
  const __half* wp2 = w16 + (size_t)(q_sub * 45) * HH + (wid << 5) + (hq << 2);

  double lp_acc = 0.0, ent_acc = 0.0;
  int first_idx = 0;

  for (int t = 0; t < SS; ++t) {
    // ================== FUSED P2+P3 (+ q12 prefetch) ==================
    const int p0 = hist[1], p1 = hist[2];
    uint2 g0raw = make_uint2(0, 0), g1raw = make_uint2(0, 0);
    const bool pf = (tid < 90);
    if (pf) {
      if (p0 >= 0) g0raw = *(const uint2*)(Gb + ((size_t)p0 * 3 + 0) * QQ + 4 * tid);
      if (p1 >= 0) g1raw = *(const uint2*)(Gb + ((size_t)p1 * 3 + 1) * QQ + 4 * tid);
    }

    // ---- P2: eq over own 32-h slice; lane covers 4 h, 45 q ----
    float a0 = 0.f, a1 = 0.f, a2 = 0.f, a3 = 0.f;
    {
      const float* qsp = q_s + q_sub * 45;
#pragma unroll 9
      for (int i = 0; i < 45; ++i) {
        uint2 raw = *(const uint2*)(wp2 + (size_t)i * HH);
        float2 f01 = __half22float2(*(const __half2*)&raw.x);
        float2 f23 = __half22float2(*(const __half2*)&raw.y);
        float qv = qsp[i];
        a0 = fmaf(qv, f01.x, a0); a1 = fmaf(qv, f01.y, a1);
        a2 = fmaf(qv, f23.x, a2); a3 = fmaf(qv, f23.y, a3);
      }
#pragma unroll
      for (int off = 8; off <= 32; off <<= 1) {
        a0 += __shfl_xor(a0, off);
        a1 += __shfl_xor(a1, off);
        a2 += __shfl_xor(a2, off);
        a3 += __shfl_xor(a3, off);
      }
      if (lane < 8) {        // q_sub==0, hq==lane
        int h0 = (wid << 5) + (lane << 2);
        evq[h0 + 0].x = CC * a0;
        evq[h0 + 1].x = CC * a1;
        evq[h0 + 2].x = CC * a2;
        evq[h0 + 3].x = CC * a3;
      }
      // no barrier: each wave reads only its own evq slice (in-wave ordering)
    }

    // ---- P3: scores from register-resident enc ----
    {
      float acc[8];
#pragma unroll
      for (int j = 0; j < 8; ++j) acc[j] = 0.f;
#pragma unroll
      for (int i = 0; i < 16; ++i) {
        float2 ev = evq[(wid << 5) + 2 * i + hl];
        const float eqC = ev.x, mv = ev.y;
        const uint32_t w0 = enc_r[i].x, w1 = enc_r[i].y;
#pragma unroll
        for (int k = 0; k < 4; ++k) {
          {
            float f = (float)(int)(int8_t)(w0 >> (8 * k));
            float e = EXP2F(fmaf(f, ENC_INV, eqC));
            acc[k] = fmaf(mv, frcp(e + 1.0f), acc[k]);
          }
          {
            float f = (float)(int)(int8_t)(w1 >> (8 * k));
            float e = EXP2F(fmaf(f, ENC_INV, eqC));
            acc[4 + k] = fmaf(mv, frcp(e + 1.0f), acc[4 + k]);
          }
        }
      }
#pragma unroll
      for (int j = 0; j < 8; ++j) acc[j] += __shfl_xor(acc[j], 32);
      if (hl == 0) {
        *(float4*)&part[wid][sbase]     = make_float4(acc[0], acc[1], acc[2], acc[3]);
        *(float4*)&part[wid][sbase + 4] = make_float4(acc[4], acc[5], acc[6], acc[7]);
      }
    }

    // ---- consume q12 prefetch ----
    if (pf) {
      float2 f0a = __half22float2(*(const __half2*)&g0raw.x);
      float2 f0b = __half22float2(*(const __half2*)&g0raw.y);
      float2 f1a = __half22float2(*(const __half2*)&g1raw.x);
      float2 f1b = __half22float2(*(const __half2*)&g1raw.y);
      float4 qv;
      qv.x = f0a.x + f1a.x; qv.y = f0a.y + f1a.y;
      qv.z = f0b.x + f1b.x; qv.w = f0b.y + f1b.y;
      *(float4*)&q12_s[4 * tid] = qv;
    }
    __syncthreads();   // b1: part, q12 ready

    // ================== P4: 4 waves, 1 threefry/thread ==================
    if (tid < SS) {
      const int s = tid;
      float sc = Vtot;
#pragma unroll
      for (int r = 0; r < 16; ++r) sc += part[r][s];
      float logit = 10.0f * fast_tanh(sc);
      float m = (mask_s[s] != 0.f) ? -1.0e8f : logit;
      m_s[s] = m;
      TF2 o = threefry(c_keys.sk[t][0], c_keys.sk[t][1], 0u, (uint32_t)(b * SS + s));
      float fb = __uint_as_float((o.b >> 9) | 0x3f800000u) - 1.0f;
      fb = fmaxf(fb, 1.0e-12f);
      float g = -__logf(-__logf(fb));
      float z = m + g;
      float e = __expf(m);          // masked -> exactly 0
      float em = e * m;             // 0 * -1e8 = -0
      int si = s;
#pragma unroll
      for (int off = 32; off; off >>= 1) {
        float zo = __shfl_xor(z, off);
        int io = __shfl_xor(si, off);
        if (zo > z || (zo == z && io < si)) { z = zo; si = io; }
        e += __shfl_xor(e, off);
        em += __shfl_xor(em, off);
      }
      if (lane == 0) wred[wid] = make_float4(z, __int_as_float(si), e, em);
    }
    __syncthreads();   // b2: wred, m_s ready

    // ================== finalize (all threads) + next-q build ==================
    {
      float4 r0 = wred[0], r1 = wred[1], r2 = wred[2], r3 = wred[3];
      float z = r0.x; int si = __float_as_int(r0.y);
      {
        int i1 = __float_as_int(r1.y);
        if (r1.x > z || (r1.x == z && i1 < si)) { z = r1.x; si = i1; }
        int i2 = __float_as_int(r2.y);
        if (r2.x > z || (r2.x == z && i2 < si)) { z = r2.x; si = i2; }
        int i3 = __float_as_int(r3.y);
        if (r3.x > z || (r3.x == z && i3 < si)) { z = r3.x; si = i3; }
      }
      const int idx = si;
      if (pf) {   // tid < 90: q_s = relu(q12 + G2[idx])
        uint2 g2 = *(const uint2*)(Gb + ((size_t)idx * 3 + 2) * QQ + 4 * tid);
        float2 f2a = __half22float2(*(const __half2*)&g2.x);
        float2 f2b = __half22float2(*(const __half2*)&g2.y);
        float4 q12v = *(const float4*)&q12_s[4 * tid];
        float4 qn;
        qn.x = fmaxf(q12v.x + f2a.x, 0.f);
        qn.y = fmaxf(q12v.y + f2a.y, 0.f);
        qn.z = fmaxf(q12v.z + f2b.x, 0.f);
        qn.w = fmaxf(q12v.w + f2b.y, 0.f);
        *(float4*)&q_s[4 * tid] = qn;
      }
      if (tid == 0) {
        float se = r0.z + r1.z + r2.z + r3.z;
        float sem = r0.w + r1.w + r2.w + r3.w;
        float lse = __logf(se);
        float mi = m_s[idx];
        lp_acc += (double)(mi - lse);
        ent_acc += (double)(lse - sem / se);
        out[b * 257 + t] = (float)idx;
        mask_s[idx] = 1.0f;
        hist[0] = hist[1]; hist[1] = hist[2]; hist[2] = idx;
        if (t == 0) first_idx = idx;
      }
    }
    __syncthreads();   // b3: q_s, hist, mask updated
  }

  if (tid == 0) {
    out[b * 257 + 256] = (float)first_idx;
    lpb[b] = lp_acc;
    entb[b] = ent_acc;
  }
}

// ---------------- Final deterministic reduction ----------------
__global__ void k_final(const double* __restrict__ lpb,
                        const double* __restrict__ entb, float* __restrict__ out) {
  if (threadIdx.x == 0) {
    double a = 0.0, c = 0.0;
    for (int i = 0; i < BB; ++i) { a += lpb[i]; c += entb[i]; }
    out[BB * 257 + 0] = (float)a;
    out[BB * 257 + 1] = (float)c;
  }
}

extern "C" void kernel_launch(void* const* d_in, const int* in_sizes, int n_in,
                              void* d_out, int out_size, void* d_ws, size_t ws_size,
                              hipStream_t stream) {
  const float* inputs = (const float*)d_in[0];
  const float* Wc  = (const float*)d_in[1];
  const float* bc  = (const float*)d_in[2];
  const float* Wq  = (const float*)d_in[3];
  const float* w_q = (const float*)d_in[4];
  const float* v   = (const float*)d_in[5];
  float* out = (float*)d_out;

  char* ws = (char*)d_ws;
  const size_t encBytes = (size_t)BB * HH * SS;            // 16.8 MB int8
  const size_t gBytes   = (size_t)3 * BB * SS * QQ * 2;    // 70.8 MB fp16
  const size_t wqBytes  = (size_t)QQ * HH * 2;             // 369 KB fp16
  int8_t* enc8 = (int8_t*)ws;
  __half* G   = (__half*)(ws + encBytes);
  __half* w16 = (__half*)(ws + encBytes + gBytes);
  size_t goff = (encBytes + gBytes + wqBytes + 1023) & ~(size_t)1023;
  double* lpb = (double*)(ws + goff);
  double* entb = lpb + BB;

  dim3 gA1(8, BB);
  k_enc<<<gA1, 256, 0, stream>>>(inputs, Wc, bc, enc8);
  dim3 gA2(6, BB, 3);
  k_G<<<gA2, 256, 0, stream>>>(inputs, Wq, G);
  k_wq16<<<180, 1024, 0, stream>>>(w_q, w16);
  k_scan<<<BB, 1024, 0, stream>>>(w16, v, enc8, G, out, lpb, entb);
  k_final<<<1, 64, 0, stream>>>(lpb, entb, out);
}